// Round 5
// baseline (238.455 us; speedup 1.0000x reference)
//
#include <hip/hip_runtime.h>
#include <hip/hip_bf16.h>
#include <cstdint>

// Problem constants
#define B_DIM 16384
#define DX 256
#define DH 512
#define DS 128
#define DT 128
#define KDIM 1024   // DX+DH+DS+DT
#define NDIM 2048   // 4*DH
#define HOUT 512

typedef __attribute__((ext_vector_type(8))) short short8;
typedef __attribute__((ext_vector_type(4))) float floatx4;

union bf16x8 {
  short8 v;
  __hip_bfloat16 b[8];
};

__device__ __forceinline__ float fast_sigmoid(float x) {
  return 1.f / (1.f + __expf(-x));
}
__device__ __forceinline__ float fast_tanh(float x) {
  float e = __expf(-2.f * x);
  return (1.f - e) / (1.f + e);
}

// ===========================================================================
// Chunk-flat packed operands with BAKED-IN XOR bank swizzle (verified r4).
//   A tile (mb,kb) = 256 rows x 64 k = 32 chunks of 512 bf16 (1KB).
//   chunk t32 = s*16 + c  (s = 32-k panel, c = 16-row group), lane i (0..63):
//     row = c*16 + i/4, kq_lin = i&3, kq_src = kq_lin ^ ((row>>1)&3)
//     holds A[mb*256+row][kb*64 + s*32 + kq_src*8 .. +7]
//   flat = ((mb*16+kb)*32 + t32)*512 + i*8
//   GEMM stages with contiguous per-lane addrs (GLD dest = linear LDS
//   [s][row][kq_lin][8]); fragment read at kq_lin = q ^ ((row>>1)&3)
//   -> 0 bank conflicts (verified r2/r4).
// W tile (nblk,kb) = 128 packed cols x 64 k, 16 chunks (identical to r4):
//   pcol = wn*64 + g*16 + hl  <->  orig col = g*512 + (nblk*32 + wn*16 + hl)
//   (g: 0=i,1=f,2=o,3=c~) -> gate g = wave col-frag index -> register epilogue.
// ===========================================================================

__global__ __launch_bounds__(256) void pack_AW(
    const float* __restrict__ x, const float* __restrict__ h,
    const float* __restrict__ sp_, const float* __restrict__ tp_,
    const float* __restrict__ Wx, const float* __restrict__ Wh,
    const float* __restrict__ Ws, const float* __restrict__ Wt,
    __hip_bfloat16* __restrict__ Ap, __hip_bfloat16* __restrict__ Wp) {
  const int NA = B_DIM * KDIM / 8 / 256;   // 8192 A-blocks
  const int bid = blockIdx.x;
  if (bid < NA) {
    // ---- pack A: 256-row tiles ----
    int tid = bid * 256 + threadIdx.x;     // 0 .. B_DIM*KDIM/8-1
    int i = tid & 63;
    int t32 = (tid >> 6) & 31;
    int tile = tid >> 11;                  // mb*16 + kb
    int kb = tile & 15, mb = tile >> 4;    // mb 0..63
    int s = t32 >> 4, c = t32 & 15;
    int row = c * 16 + (i >> 2);           // 0..255
    int kq = (i & 3) ^ ((row >> 1) & 3);   // baked swizzle
    int b = mb * 256 + row;
    int k = kb * 64 + s * 32 + kq * 8;
    const float* p;
    if (k < 768) {
      p = (k < 256) ? (x + (size_t)b * DX + k) : (h + (size_t)b * DH + (k - 256));
    } else {
      p = (k < 896) ? (sp_ + (size_t)b * DS + (k - 768))
                    : (tp_ + (size_t)b * DT + (k - 896));
    }
    floatx4 v0 = *(const floatx4*)p;
    floatx4 v1 = *(const floatx4*)(p + 4);
    bf16x8 o;
#pragma unroll
    for (int j = 0; j < 4; ++j) {
      o.b[j]     = __float2bfloat16(v0[j]);
      o.b[4 + j] = __float2bfloat16(v1[j]);
    }
    *(short8*)(Ap + (size_t)tid * 8) = o.v;
  } else {
    // ---- pack W: unchanged from round 4 ----
    int tid = (bid - NA) * 256 + threadIdx.x;  // 0 .. NDIM*KDIM/8-1
    int i = tid & 63;
    int t16 = (tid >> 6) & 15;
    int tile = tid >> 10;                  // nblk*16 + kb
    int kb = tile & 15, nblk = tile >> 4;
    int s = t16 >> 3, c = t16 & 7;
    int pcol = c * 16 + (i >> 2);          // 0..127
    int kq = (i & 3) ^ ((pcol >> 1) & 3);  // baked swizzle
    int k = kb * 64 + s * 32 + kq * 8;
    int wn = pcol >> 6, g = (pcol >> 4) & 3, hl = pcol & 15;
    int col = g * 512 + nblk * 32 + wn * 16 + hl;
    const float* src; int kl;
    if (k < 256)      { src = Wx; kl = k; }
    else if (k < 768) { src = Wh; kl = k - 256; }
    else if (k < 896) { src = Ws; kl = k - 768; }
    else              { src = Wt; kl = k - 896; }
    bf16x8 o;
#pragma unroll
    for (int r = 0; r < 8; ++r)
      o.b[r] = __float2bfloat16(src[(size_t)(kl + r) * NDIM + col]);
    *(short8*)(Wp + (size_t)tid * 8) = o.v;
  }
}

// ---------------------------------------------------------------------------
// Round-4 skeleton, re-tiled: BM=256 x BN=128, BK=64, 256 threads, 4 waves
// (2M x 2N), each wave owns 128x64 output = 8x4 acc of 16x16 MFMA.
// Balanced pipes per 32-k panel/wave: 12 ds_read_b128 (~144cy) : 32 MFMA
// (~155cy), vs round-4's 8:16 (96:78, LDS-read-bound).
// Per iter: 12 wave-level GLDs (32KB A + 16KB B, contiguous), __syncthreads,
// 2x{12 ds_read + 32 MFMA}, __syncthreads. 48 KB LDS, ~2 blocks/CU.
// ---------------------------------------------------------------------------
#define GLD(src, dst)                                              \
  __builtin_amdgcn_global_load_lds(                                \
      (const __attribute__((address_space(1))) void*)(src),        \
      (__attribute__((address_space(3))) void*)(dst), 16, 0, 0)

__global__ __launch_bounds__(256, 2) void lstm_gemm(
    const __hip_bfloat16* __restrict__ Ap, const __hip_bfloat16* __restrict__ Wp,
    const float* __restrict__ bh, const float* __restrict__ c_in,
    float* __restrict__ out) {
  __shared__ unsigned short As[16384];  // 32 KB: [s:2][row:256][kq:4][8]
  __shared__ unsigned short Bs[8192];   // 16 KB: [s:2][pcol:128][kq:4][8]

  const int tid = threadIdx.x;
  const int lane = tid & 63;
  const int wid = tid >> 6;      // 0..3
  const int wm = wid & 1;        // row half (128 rows of 256)
  const int wn = wid >> 1;       // col half (64 packed cols of 128)
  const int q = lane >> 4;
  const int fr = lane & 15;

  // XCD-aware bijective swizzle (1024 blocks, 1024%8==0)
  const int bid = blockIdx.x;
  const int wg = (bid & 7) * 128 + (bid >> 3);
  const int mb = wg >> 4;        // 0..63
  const int nblk = wg & 15;      // 0..15
  const int m0 = mb * 256;

  // Fragment read offsets (ushort idx within a 32-k panel), XOR-swizzled.
  int aOff[8], bOff[4];
#pragma unroll
  for (int m = 0; m < 8; ++m) {
    int row = wm * 128 + m * 16 + fr;
    aOff[m] = row * 32 + (q ^ ((row >> 1) & 3)) * 8;
  }
#pragma unroll
  for (int n = 0; n < 4; ++n) {
    int colc = wn * 64 + n * 16 + fr;
    bOff[n] = colc * 32 + (q ^ ((colc >> 1) & 3)) * 8;
  }

  floatx4 acc[8][4];
#pragma unroll
  for (int i = 0; i < 8; ++i)
#pragma unroll
    for (int j = 0; j < 4; ++j) acc[i][j] = (floatx4)0.f;

  const __hip_bfloat16* aTile = Ap + (size_t)(mb * 16) * 16384 + lane * 8;
  const __hip_bfloat16* bTile = Wp + (size_t)(nblk * 16) * 8192 + lane * 8;

  for (int kb = 0; kb < 16; ++kb) {
    const __hip_bfloat16* ap = aTile + (size_t)kb * 16384;
    const __hip_bfloat16* bp = bTile + (size_t)kb * 8192;
    // 32 A-chunks + 16 B-chunks of 1KB, wave-uniform split: 8A + 4B per wave.
#pragma unroll
    for (int j = 0; j < 8; ++j) {
      const int ca = wid * 8 + j;
      GLD(ap + ca * 512, &As[ca * 512]);
    }
#pragma unroll
    for (int j = 0; j < 4; ++j) {
      const int cb = wid * 4 + j;
      GLD(bp + cb * 512, &Bs[cb * 512]);
    }
    __syncthreads();

#pragma unroll
    for (int s = 0; s < 2; ++s) {
      short8 af[8], bf[4];
#pragma unroll
      for (int i = 0; i < 8; ++i)
        af[i] = *(const short8*)&As[s * 8192 + aOff[i]];
#pragma unroll
      for (int i = 0; i < 4; ++i)
        bf[i] = *(const short8*)&Bs[s * 4096 + bOff[i]];
#pragma unroll
      for (int mi = 0; mi < 8; ++mi)
#pragma unroll
        for (int ni = 0; ni < 4; ++ni)
          acc[mi][ni] = __builtin_amdgcn_mfma_f32_16x16x32_bf16(
              af[mi], bf[ni], acc[mi][ni], 0, 0, 0);
    }
    __syncthreads();
  }

  // ---- In-register epilogue ----
  // acc[mi][g]: rows m0 + wm*128 + mi*16 + q*4 + r, gate g of hidden hh.
  const int hh = nblk * 32 + wn * 16 + fr;
  float bias[4];
#pragma unroll
  for (int g = 0; g < 4; ++g) bias[g] = bh[g * 512 + hh];

#pragma unroll
  for (int mi = 0; mi < 8; ++mi) {
#pragma unroll
    for (int r = 0; r < 4; ++r) {
      const size_t grow = (size_t)(m0 + wm * 128 + mi * 16 + q * 4 + r);
      const float pi = acc[mi][0][r] + bias[0];
      const float pf = acc[mi][1][r] + bias[1];
      const float po = acc[mi][2][r] + bias[2];
      const float pc = acc[mi][3][r] + bias[3];
      const float ig = fast_sigmoid(pi);
      const float fg = fast_sigmoid(pf);
      const float og = fast_sigmoid(po);
      const float cg = fast_tanh(pc);
      const float cc = fg * c_in[grow * HOUT + hh] + ig * cg;
      out[grow * HOUT + hh] = fast_tanh(og * cc);  // faithful: tanh(o*c_new)
      out[(size_t)B_DIM * HOUT + grow * HOUT + hh] = cc;
    }
  }
}

// ---------------------------------------------------------------------------
extern "C" void kernel_launch(void* const* d_in, const int* in_sizes, int n_in,
                              void* d_out, int out_size, void* d_ws, size_t ws_size,
                              hipStream_t stream) {
  const float* x  = (const float*)d_in[0];
  const float* h  = (const float*)d_in[1];
  const float* c  = (const float*)d_in[2];
  const float* sp = (const float*)d_in[3];
  const float* tp = (const float*)d_in[4];
  const float* Wx = (const float*)d_in[5];
  const float* Wh = (const float*)d_in[6];
  const float* bh = (const float*)d_in[7];
  const float* Ws = (const float*)d_in[8];
  const float* Wt = (const float*)d_in[9];
  float* out = (float*)d_out;

  __hip_bfloat16* Ap = (__hip_bfloat16*)d_ws;                                     // 32 MB
  __hip_bfloat16* Wp = (__hip_bfloat16*)((char*)d_ws + (size_t)B_DIM * KDIM * 2); // 4 MB

  const int nblk_A = B_DIM * KDIM / 8 / 256;   // 8192
  const int nblk_W = NDIM * KDIM / 8 / 256;    // 1024
  pack_AW<<<dim3(nblk_A + nblk_W), dim3(256), 0, stream>>>(
      x, h, sp, tp, Wx, Wh, Ws, Wt, Ap, Wp);
  lstm_gemm<<<dim3(1024), dim3(256), 0, stream>>>(Ap, Wp, bh, c, out);
}